// Round 2
// baseline (567.818 us; speedup 1.0000x reference)
//
#include <hip/hip_runtime.h>
#include <stdint.h>

#define Bn 16
#define C 64
#define H 256
#define W 256
#define HW (H * W)          // 65536
#define NHW (Bn * HW)       // 1048576

// Fused-kernel tile geometry: 64 wide x 16 high, 256 threads, 4 px/thread.
#define TW 64
#define TH 16
#define SZH 18              // TH + 2 halo rows
#define SZW 73              // 72 used cols (gw0-4 .. gw0+67), +1 pad vs bank conflicts

typedef float f32x4 __attribute__((ext_vector_type(4)));

// ---------------------------------------------------------------------------
// Kernel 1: weight prep. One wave per output channel o.
// wbits[o*9+tap] bit c = (w[o][c][tap] > 0); scale[o] = mean|w| over 576.
// edgeL/edgeR[o] = 2 * sum popc over left/right column taps (border fixups).
// ---------------------------------------------------------------------------
__global__ void prep_weights(const float* __restrict__ w,
                             uint64_t* __restrict__ wbits,
                             float* __restrict__ scale,
                             int* __restrict__ edgeL,
                             int* __restrict__ edgeR) {
    int o = blockIdx.x;     // 64 blocks
    int c = threadIdx.x;    // 64 threads = 1 wave
    const float* wp = w + ((size_t)o * C + c) * 9;
    float asum = 0.f;
    uint64_t m[9];
#pragma unroll
    for (int tap = 0; tap < 9; ++tap) {
        float v = wp[tap];
        asum += fabsf(v);
        m[tap] = __ballot(v > 0.f);   // uniform across the wave
    }
    if (c == 0) {
#pragma unroll
        for (int tap = 0; tap < 9; ++tap) wbits[o * 9 + tap] = m[tap];
        edgeL[o] = 2 * (int)(__popcll(m[0]) + __popcll(m[3]) + __popcll(m[6]));
        edgeR[o] = 2 * (int)(__popcll(m[2]) + __popcll(m[5]) + __popcll(m[8]));
    }
#pragma unroll
    for (int off = 32; off > 0; off >>= 1)
        asum += __shfl_down(asum, off);
    if (c == 0) scale[o] = asum * (1.f / 576.f);
}

// ---------------------------------------------------------------------------
// Kernel 2 (fused): per-block pack z (tile + 1px halo) into LDS, then binary
// conv + RPReLU + residual. x is read ONCE from HBM (pack); the identity
// re-read hits L2/LLC (x totals exactly 256 MB = LLC size; out stores are
// nontemporal so they don't evict it). No global zbits round-trip.
// Halo chunks are 4-col aligned and the image border (0/256) is 4-aligned,
// so every 4-col chunk is either fully inside the image or fully outside
// (-> zeros). Out-of-image z-words are 0; column corrections via edgeL/R,
// row borders via the masked slow path (verified in earlier rounds).
// ---------------------------------------------------------------------------
__global__ __launch_bounds__(256) void bconv_fused(
        const uint64_t* __restrict__ wbits,
        const float* __restrict__ scale,
        const int* __restrict__ edgeL,
        const int* __restrict__ edgeR,
        const float* __restrict__ x,
        const float* __restrict__ bias,
        const float* __restrict__ pb0,
        const float* __restrict__ aw,
        const float* __restrict__ pb1,
        float* __restrict__ out) {
    __shared__ uint64_t swb[640];          // weights padded to 10/u64 per o (16B-aligned rows)
    __shared__ uint64_t sz[SZH * SZW];     // packed z tile + halo
    __shared__ float4 sprm[C];             // {scale, pb0, a, pb1}
    __shared__ float sbias[C];
    __shared__ int sEL[C], sER[C];

    int t = threadIdx.x;
    if (t < C) {
        sprm[t] = make_float4(scale[t], pb0[t], aw[t], pb1[t]);
        sbias[t] = bias[t];
        sEL[t] = edgeL[t];
        sER[t] = edgeR[t];
    }
    for (int i = t; i < 576; i += 256) {
        int o = i / 9;
        swb[o * 10 + (i - o * 9)] = wbits[i];
    }

    int bid = blockIdx.x;                  // 1024 blocks
    int n = bid >> 6;                      // image
    int tile = bid & 63;
    int ty = tile >> 2, tx = tile & 3;     // 4 tiles across, 16 down
    int gh0 = ty * TH, gw0 = tx * TW;

    const float* xn = x + (size_t)n * C * HW;

    __syncthreads();                       // sbias ready

    // ---- phase 1: pack z into LDS (18 rows x 18 four-col chunks) ----------
    for (int ci = t; ci < SZH * 18; ci += 256) {
        int r = ci / 18;
        int cb = (ci - r * 18) * 4;        // col offset within sz row
        int gh = gh0 + r - 1;
        int gwb = gw0 - 4 + cb;            // global col of chunk base (4-aligned)
        uint64_t b0 = 0, b1 = 0, b2 = 0, b3 = 0;
        if ((unsigned)gh < (unsigned)H && (unsigned)gwb < (unsigned)(W - 3)) {
            const float* xp = xn + gh * W + gwb;
#pragma unroll 8
            for (int ch = 0; ch < C; ++ch) {
                f32x4 v = *reinterpret_cast<const f32x4*>(xp + (size_t)ch * HW);
                float bc = sbias[ch];
                b0 |= (uint64_t)(v.x + bc > 0.f) << ch;
                b1 |= (uint64_t)(v.y + bc > 0.f) << ch;
                b2 |= (uint64_t)(v.z + bc > 0.f) << ch;
                b3 |= (uint64_t)(v.w + bc > 0.f) << ch;
            }
        }
        uint64_t* zp = &sz[r * SZW + cb];
        zp[0] = b0; zp[1] = b1; zp[2] = b2; zp[3] = b3;
    }
    __syncthreads();

    // ---- phase 2: load this thread's 3x6 z window from LDS ----------------
    int tr = t >> 4;                       // tile row 0..15
    int tc4 = (t & 15) * 4;                // tile col base (4 px/thread)
    int gh = gh0 + tr;
    int gw = gw0 + tc4;

    uint64_t zb[3][6];
#pragma unroll
    for (int i = 0; i < 3; ++i)
#pragma unroll
        for (int j = 0; j < 6; ++j)
            zb[i][j] = sz[(tr + i) * SZW + tc4 + 3 + j];  // col gw-1+j

    const float* xid = xn + gh * W + gw;
    float* op = out + (size_t)n * C * HW + gh * W + gw;
    bool leftE  = (gw == 0);
    bool rightE = (gw == W - 4);

    // ---- phase 3: o-loop ---------------------------------------------------
    if (gh >= 1 && gh <= H - 2) {
        // fast path (all rows valid); identity loads pipelined 2 deep
        f32x4 id0 = *reinterpret_cast<const f32x4*>(xid);
        f32x4 id1 = *reinterpret_cast<const f32x4*>(xid + HW);
#pragma unroll 2
        for (int o = 0; o < C; ++o) {
            const uint64_t* wp = &swb[o * 10];
            int s0 = 0, s1 = 0, s2 = 0, s3 = 0;
#pragma unroll
            for (int i = 0; i < 3; ++i)
#pragma unroll
                for (int jj = 0; jj < 3; ++jj) {
                    uint64_t wt = wp[i * 3 + jj];
                    s0 += (int)__popcll(wt ^ zb[i][jj]);
                    s1 += (int)__popcll(wt ^ zb[i][jj + 1]);
                    s2 += (int)__popcll(wt ^ zb[i][jj + 2]);
                    s3 += (int)__popcll(wt ^ zb[i][jj + 3]);
                }
            int d0 = 576 - 2 * s0, d1 = 576 - 2 * s1;
            int d2 = 576 - 2 * s2, d3 = 576 - 2 * s3;
            if (leftE)  d0 += sEL[o] - 192;
            if (rightE) d3 += sER[o] - 192;

            float4 pr = sprm[o];
            f32x4 idv = id0;
            id0 = id1;
            if (o < C - 2)
                id1 = *reinterpret_cast<const f32x4*>(xid + (size_t)(o + 2) * HW);
            f32x4 r;
            float y;
            y = pr.x * (float)d0 + pr.y; y = y > 0.f ? y : pr.z * y; r.x = y + pr.w + idv.x;
            y = pr.x * (float)d1 + pr.y; y = y > 0.f ? y : pr.z * y; r.y = y + pr.w + idv.y;
            y = pr.x * (float)d2 + pr.y; y = y > 0.f ? y : pr.z * y; r.z = y + pr.w + idv.z;
            y = pr.x * (float)d3 + pr.y; y = y > 0.f ? y : pr.z * y; r.w = y + pr.w + idv.w;
            __builtin_nontemporal_store(r, reinterpret_cast<f32x4*>(op + (size_t)o * HW));
        }
    } else {
        // slow path: gh==0 or gh==255 (one wave per top/bottom tile), masked
        int vrow[3], vcol[6];
#pragma unroll
        for (int i = 0; i < 3; ++i)
            vrow[i] = ((unsigned)(gh - 1 + i) < (unsigned)H) ? -1 : 0;
#pragma unroll
        for (int j = 0; j < 6; ++j)
            vcol[j] = ((unsigned)(gw - 1 + j) < (unsigned)W) ? -1 : 0;
        int nv[4];
#pragma unroll
        for (int q = 0; q < 4; ++q) {
            int nr = (vrow[0] & 1) + (vrow[1] & 1) + (vrow[2] & 1);
            int nc = (vcol[q] & 1) + (vcol[q + 1] & 1) + (vcol[q + 2] & 1);
            nv[q] = nr * nc;
        }
#pragma unroll 2
        for (int o = 0; o < C; ++o) {
            const uint64_t* wp = &swb[o * 10];
            int s[4] = {0, 0, 0, 0};
#pragma unroll
            for (int i = 0; i < 3; ++i)
#pragma unroll
                for (int jj = 0; jj < 3; ++jj) {
                    uint64_t wt = wp[i * 3 + jj];
#pragma unroll
                    for (int q = 0; q < 4; ++q)
                        s[q] += (vrow[i] & vcol[q + jj]) &
                                (int)__popcll(wt ^ zb[i][q + jj]);
                }
            float4 pr = sprm[o];
            f32x4 idv = *reinterpret_cast<const f32x4*>(xid + (size_t)o * HW);
            f32x4 r;
            float y;
            y = pr.x * (float)(64 * nv[0] - 2 * s[0]) + pr.y; y = y > 0.f ? y : pr.z * y; r.x = y + pr.w + idv.x;
            y = pr.x * (float)(64 * nv[1] - 2 * s[1]) + pr.y; y = y > 0.f ? y : pr.z * y; r.y = y + pr.w + idv.y;
            y = pr.x * (float)(64 * nv[2] - 2 * s[2]) + pr.y; y = y > 0.f ? y : pr.z * y; r.z = y + pr.w + idv.z;
            y = pr.x * (float)(64 * nv[3] - 2 * s[3]) + pr.y; y = y > 0.f ? y : pr.z * y; r.w = y + pr.w + idv.w;
            __builtin_nontemporal_store(r, reinterpret_cast<f32x4*>(op + (size_t)o * HW));
        }
    }
}

// ---------------------------------------------------------------------------
extern "C" void kernel_launch(void* const* d_in, const int* in_sizes, int n_in,
                              void* d_out, int out_size, void* d_ws, size_t ws_size,
                              hipStream_t stream) {
    const float* x           = (const float*)d_in[0];
    const float* move0_bias  = (const float*)d_in[1];
    const float* conv_weight = (const float*)d_in[2];
    const float* prelu_w     = (const float*)d_in[3];
    const float* pr_bias0    = (const float*)d_in[4];
    const float* pr_bias1    = (const float*)d_in[5];
    float* out = (float*)d_out;

    uint8_t* ws = (uint8_t*)d_ws;
    uint64_t* wbits = (uint64_t*)ws;                     // 4608 B
    float* scale    = (float*)(ws + 4608);               // 256 B
    int* edgeL      = (int*)(ws + 4864);                 // 256 B
    int* edgeR      = (int*)(ws + 5120);                 // 256 B

    prep_weights<<<64, 64, 0, stream>>>(conv_weight, wbits, scale, edgeL, edgeR);
    bconv_fused<<<Bn * (H / TH) * (W / TW), 256, 0, stream>>>(
        wbits, scale, edgeL, edgeR, x, move0_bias,
        pr_bias0, prelu_w, pr_bias1, out);
}

// Round 3
// 559.860 us; speedup vs baseline: 1.0142x; 1.0142x over previous
//
#include <hip/hip_runtime.h>
#include <stdint.h>

#define Bn 16
#define C 64
#define H 256
#define W 256
#define HW (H * W)          // 65536
#define NHW (Bn * HW)       // 1048576

// Fused-kernel tile geometry: 64 wide x 16 high, 512 threads, 2 px/thread.
#define TW 64
#define TH 16
#define SZH 18              // TH + 2 halo rows
#define SZW 73              // 72 used cols (gw0-4 .. gw0+67), +1 pad

typedef float f32x4 __attribute__((ext_vector_type(4)));
typedef float f32x2 __attribute__((ext_vector_type(2)));

// ---------------------------------------------------------------------------
// Kernel 1: weight prep. One wave per output channel o.
// wbits[o*9+tap] bit c = (w[o][c][tap] > 0); scale[o] = mean|w| over 576.
// edgeL/edgeR[o] = 2 * sum popc over left/right column taps (border fixups).
// ---------------------------------------------------------------------------
__global__ void prep_weights(const float* __restrict__ w,
                             uint64_t* __restrict__ wbits,
                             float* __restrict__ scale,
                             int* __restrict__ edgeL,
                             int* __restrict__ edgeR) {
    int o = blockIdx.x;     // 64 blocks
    int c = threadIdx.x;    // 64 threads = 1 wave
    const float* wp = w + ((size_t)o * C + c) * 9;
    float asum = 0.f;
    uint64_t m[9];
#pragma unroll
    for (int tap = 0; tap < 9; ++tap) {
        float v = wp[tap];
        asum += fabsf(v);
        m[tap] = __ballot(v > 0.f);   // uniform across the wave
    }
    if (c == 0) {
#pragma unroll
        for (int tap = 0; tap < 9; ++tap) wbits[o * 9 + tap] = m[tap];
        edgeL[o] = 2 * (int)(__popcll(m[0]) + __popcll(m[3]) + __popcll(m[6]));
        edgeR[o] = 2 * (int)(__popcll(m[2]) + __popcll(m[5]) + __popcll(m[8]));
    }
#pragma unroll
    for (int off = 32; off > 0; off >>= 1)
        asum += __shfl_down(asum, off);
    if (c == 0) scale[o] = asum * (1.f / 576.f);
}

// ---------------------------------------------------------------------------
// Kernel 2 (fused): pack z (tile + 1px halo) into LDS, then binary conv +
// RPReLU + residual. 512 threads, 2 px/thread -> 100% occupancy cap.
// Weights/params read as wave-uniform global loads (-> s_load, scalar cache),
// so the o-loop touches no LDS. Out-of-image z-words are 0; column borders
// fixed via edgeL/R on the unmasked sum; row borders take the fully-masked
// path, widened to whole waves so the branch is wave-uniform.
// ---------------------------------------------------------------------------
__global__ __launch_bounds__(512, 8) void bconv_fused(
        const uint64_t* __restrict__ wbits,
        const float* __restrict__ scale,
        const int* __restrict__ edgeL,
        const int* __restrict__ edgeR,
        const float* __restrict__ x,
        const float* __restrict__ bias,
        const float* __restrict__ pb0,
        const float* __restrict__ aw,
        const float* __restrict__ pb1,
        float* __restrict__ out) {
    __shared__ uint64_t sz[SZH * SZW];     // 10512 B

    int t = threadIdx.x;
    int bid = blockIdx.x;                  // 1024 blocks
    int n = bid >> 6;                      // image
    int tile = bid & 63;
    int ty = tile >> 2, tx = tile & 3;     // 16 down, 4 across
    int gh0 = ty * TH, gw0 = tx * TW;

    const float* xn = x + (size_t)n * C * HW;

    // ---- phase 1: pack z into LDS (18 rows x 18 four-col chunks) ----------
    if (t < SZH * 18) {
        int r = t / 18;
        int cb = (t - r * 18) * 4;         // col offset within sz row
        int gh = gh0 + r - 1;
        int gwb = gw0 - 4 + cb;            // global col of chunk base (4-aligned)
        uint64_t b0 = 0, b1 = 0, b2 = 0, b3 = 0;
        if ((unsigned)gh < (unsigned)H && (unsigned)gwb <= (unsigned)(W - 4)) {
            const float* xp = xn + gh * W + gwb;
#pragma unroll 8
            for (int ch = 0; ch < C; ++ch) {
                f32x4 v = *reinterpret_cast<const f32x4*>(xp + (size_t)ch * HW);
                float bc = bias[ch];       // uniform -> scalar load
                b0 |= (uint64_t)(v.x + bc > 0.f) << ch;
                b1 |= (uint64_t)(v.y + bc > 0.f) << ch;
                b2 |= (uint64_t)(v.z + bc > 0.f) << ch;
                b3 |= (uint64_t)(v.w + bc > 0.f) << ch;
            }
        }
        uint64_t* zp = &sz[r * SZW + cb];
        zp[0] = b0; zp[1] = b1; zp[2] = b2; zp[3] = b3;
    }
    __syncthreads();

    // ---- phase 2: this thread's 3x4 z window from LDS ----------------------
    int tr = t >> 5;                       // tile row 0..15 (32 thr/row)
    int tc2 = (t & 31) * 2;                // tile col base (2 px/thread)
    int gh = gh0 + tr;
    int gw = gw0 + tc2;

    uint64_t zb[3][4];
#pragma unroll
    for (int i = 0; i < 3; ++i)
#pragma unroll
        for (int j = 0; j < 4; ++j)
            zb[i][j] = sz[(tr + i) * SZW + tc2 + 3 + j];   // col gw-1+j

    const float* xid = xn + gh * W + gw;
    float* op = out + (size_t)n * C * HW + gh * W + gw;
    bool leftE  = (gw == 0);
    bool rightE = (gw == W - 2);

    // wave-uniform row-border predicate (a wave spans 2 tile rows)
    bool slowW = (ty == 0 && tr < 2) || (ty == 15 && tr >= 14);

    // ---- phase 3: o-loop ---------------------------------------------------
    if (!slowW) {
        f32x2 id0 = *reinterpret_cast<const f32x2*>(xid);
        f32x2 id1 = *reinterpret_cast<const f32x2*>(xid + HW);
#pragma unroll 2
        for (int o = 0; o < C; ++o) {
            const uint64_t* wp = wbits + o * 9;    // uniform -> s_load
            int s0 = 0, s1 = 0;
#pragma unroll
            for (int i = 0; i < 3; ++i)
#pragma unroll
                for (int jj = 0; jj < 3; ++jj) {
                    uint64_t wt = wp[i * 3 + jj];
                    s0 += (int)__popcll(wt ^ zb[i][jj]);
                    s1 += (int)__popcll(wt ^ zb[i][jj + 1]);
                }
            int d0 = 576 - 2 * s0, d1 = 576 - 2 * s1;
            if (leftE)  d0 += edgeL[o] - 192;
            if (rightE) d1 += edgeR[o] - 192;

            float sc = scale[o], bb0 = pb0[o], af = aw[o], bb1 = pb1[o];
            f32x2 idv = id0;
            id0 = id1;
            if (o < C - 2)
                id1 = *reinterpret_cast<const f32x2*>(xid + (size_t)(o + 2) * HW);
            f32x2 r;
            float y;
            y = sc * (float)d0 + bb0; y = y > 0.f ? y : af * y; r.x = y + bb1 + idv.x;
            y = sc * (float)d1 + bb0; y = y > 0.f ? y : af * y; r.y = y + bb1 + idv.y;
            __builtin_nontemporal_store(r, reinterpret_cast<f32x2*>(op + (size_t)o * HW));
        }
    } else {
        // masked path: exact for interior rows too (vrow all -1)
        int vrow[3], vcol[4];
#pragma unroll
        for (int i = 0; i < 3; ++i)
            vrow[i] = ((unsigned)(gh - 1 + i) < (unsigned)H) ? -1 : 0;
#pragma unroll
        for (int j = 0; j < 4; ++j)
            vcol[j] = ((unsigned)(gw - 1 + j) < (unsigned)W) ? -1 : 0;
        int nr  = (vrow[0] & 1) + (vrow[1] & 1) + (vrow[2] & 1);
        int nv0 = nr * ((vcol[0] & 1) + (vcol[1] & 1) + (vcol[2] & 1));
        int nv1 = nr * ((vcol[1] & 1) + (vcol[2] & 1) + (vcol[3] & 1));
#pragma unroll 2
        for (int o = 0; o < C; ++o) {
            const uint64_t* wp = wbits + o * 9;
            int s0 = 0, s1 = 0;
#pragma unroll
            for (int i = 0; i < 3; ++i)
#pragma unroll
                for (int jj = 0; jj < 3; ++jj) {
                    uint64_t wt = wp[i * 3 + jj];
                    s0 += (vrow[i] & vcol[jj])     & (int)__popcll(wt ^ zb[i][jj]);
                    s1 += (vrow[i] & vcol[jj + 1]) & (int)__popcll(wt ^ zb[i][jj + 1]);
                }
            float sc = scale[o], bb0 = pb0[o], af = aw[o], bb1 = pb1[o];
            f32x2 idv = *reinterpret_cast<const f32x2*>(xid + (size_t)o * HW);
            f32x2 r;
            float y;
            y = sc * (float)(64 * nv0 - 2 * s0) + bb0; y = y > 0.f ? y : af * y; r.x = y + bb1 + idv.x;
            y = sc * (float)(64 * nv1 - 2 * s1) + bb0; y = y > 0.f ? y : af * y; r.y = y + bb1 + idv.y;
            __builtin_nontemporal_store(r, reinterpret_cast<f32x2*>(op + (size_t)o * HW));
        }
    }
}

// ---------------------------------------------------------------------------
extern "C" void kernel_launch(void* const* d_in, const int* in_sizes, int n_in,
                              void* d_out, int out_size, void* d_ws, size_t ws_size,
                              hipStream_t stream) {
    const float* x           = (const float*)d_in[0];
    const float* move0_bias  = (const float*)d_in[1];
    const float* conv_weight = (const float*)d_in[2];
    const float* prelu_w     = (const float*)d_in[3];
    const float* pr_bias0    = (const float*)d_in[4];
    const float* pr_bias1    = (const float*)d_in[5];
    float* out = (float*)d_out;

    uint8_t* ws = (uint8_t*)d_ws;
    uint64_t* wbits = (uint64_t*)ws;                     // 4608 B
    float* scale    = (float*)(ws + 4608);               // 256 B
    int* edgeL      = (int*)(ws + 4864);                 // 256 B
    int* edgeR      = (int*)(ws + 5120);                 // 256 B

    prep_weights<<<64, 64, 0, stream>>>(conv_weight, wbits, scale, edgeL, edgeR);
    bconv_fused<<<Bn * (H / TH) * (W / TW), 512, 0, stream>>>(
        wbits, scale, edgeL, edgeR, x, move0_bias,
        pr_bias0, prelu_w, pr_bias1, out);
}

// Round 5
// 518.770 us; speedup vs baseline: 1.0945x; 1.0792x over previous
//
#include <hip/hip_runtime.h>
#include <stdint.h>

#define Bn 16
#define C 64
#define H 256
#define W 256
#define HW (H * W)          // 65536
#define NHW (Bn * HW)       // 1048576

// Fused-kernel tile geometry: 64 wide x 16 high, 512 threads, 2 px/thread.
#define TW 64
#define TH 16
#define SZH 18              // TH + 2 halo rows
#define SZW 73              // 72 used cols (gw0-4 .. gw0+67), +1 pad

typedef float f32x4 __attribute__((ext_vector_type(4)));
typedef float f32x2 __attribute__((ext_vector_type(2)));

// ---------------------------------------------------------------------------
// Kernel 1: weight prep. One wave per output channel o.
// wbitsP[o*10+tap] bit c = (w[o][c][tap] > 0)  (padded to 10 u64/row, 16B-aligned)
// prm[o] = {scale, pb0, aw, pb1};  edg[o] = {edgeL-192, edgeR-192}
// ---------------------------------------------------------------------------
__global__ void prep_weights(const float* __restrict__ w,
                             const float* __restrict__ pb0,
                             const float* __restrict__ aw,
                             const float* __restrict__ pb1,
                             uint64_t* __restrict__ wbitsP,
                             float4* __restrict__ prm,
                             int2* __restrict__ edg) {
    int o = blockIdx.x;     // 64 blocks
    int c = threadIdx.x;    // 64 threads = 1 wave
    const float* wp = w + ((size_t)o * C + c) * 9;
    float asum = 0.f;
    uint64_t m[9];
#pragma unroll
    for (int tap = 0; tap < 9; ++tap) {
        float v = wp[tap];
        asum += fabsf(v);
        m[tap] = __ballot(v > 0.f);   // uniform across the wave
    }
    if (c == 0) {
#pragma unroll
        for (int tap = 0; tap < 9; ++tap) wbitsP[o * 10 + tap] = m[tap];
        wbitsP[o * 10 + 9] = 0;
        edg[o] = make_int2(
            2 * (int)(__popcll(m[0]) + __popcll(m[3]) + __popcll(m[6])) - 192,
            2 * (int)(__popcll(m[2]) + __popcll(m[5]) + __popcll(m[8])) - 192);
    }
#pragma unroll
    for (int off = 32; off > 0; off >>= 1)
        asum += __shfl_down(asum, off);
    if (c == 0) prm[o] = make_float4(asum * (1.f / 576.f), pb0[o], aw[o], pb1[o]);
}

// ---------------------------------------------------------------------------
// Kernel 2 (fused): pack z (tile + 1px halo) into LDS, then binary conv +
// RPReLU + residual. 512 threads, 2 px/thread. launch_bounds(512,4):
// VGPR budget 128 so zb stays register-resident and the identity prefetch
// pipeline runs 4 deep (r3's (512,8) forced 32 VGPRs -> ILP starvation).
// Weights/params are wave-uniform s_loads. Out-of-image z-words are 0;
// column borders fixed via edg[] on the unmasked sum; row borders take the
// fully-masked path, widened to whole waves (wave-uniform branch).
// ---------------------------------------------------------------------------
__global__ __launch_bounds__(512, 4) void bconv_fused(
        const uint64_t* __restrict__ wbitsP,
        const float4* __restrict__ prm,
        const int2* __restrict__ edg,
        const float* __restrict__ x,
        const float* __restrict__ bias,
        float* __restrict__ out) {
    __shared__ uint64_t sz[SZH * SZW];     // 10512 B

    int t = threadIdx.x;
    int bid = blockIdx.x;                  // 1024 blocks
    int n = bid >> 6;                      // image
    int tile = bid & 63;
    int ty = tile >> 2, tx = tile & 3;     // 16 down, 4 across
    int gh0 = ty * TH, gw0 = tx * TW;

    const float* xn = x + (size_t)n * C * HW;

    // ---- phase 1: pack z into LDS (18 rows x 18 four-col chunks) ----------
    if (t < SZH * 18) {
        int r = t / 18;
        int cb = (t - r * 18) * 4;         // col offset within sz row
        int gh = gh0 + r - 1;
        int gwb = gw0 - 4 + cb;            // global col of chunk base (4-aligned)
        uint64_t b0 = 0, b1 = 0, b2 = 0, b3 = 0;
        if ((unsigned)gh < (unsigned)H && (unsigned)gwb <= (unsigned)(W - 4)) {
            const float* xp = xn + gh * W + gwb;
#pragma unroll 16
            for (int ch = 0; ch < C; ++ch) {
                f32x4 v = *reinterpret_cast<const f32x4*>(xp + (size_t)ch * HW);
                float bc = bias[ch];       // uniform -> scalar load
                b0 |= (uint64_t)(v.x + bc > 0.f) << ch;
                b1 |= (uint64_t)(v.y + bc > 0.f) << ch;
                b2 |= (uint64_t)(v.z + bc > 0.f) << ch;
                b3 |= (uint64_t)(v.w + bc > 0.f) << ch;
            }
        }
        uint64_t* zp = &sz[r * SZW + cb];
        zp[0] = b0; zp[1] = b1; zp[2] = b2; zp[3] = b3;
    }
    __syncthreads();

    // ---- phase 2: this thread's 3x4 z window from LDS ----------------------
    int tr = t >> 5;                       // tile row 0..15 (32 thr/row)
    int tc2 = (t & 31) * 2;                // tile col base (2 px/thread)
    int gh = gh0 + tr;
    int gw = gw0 + tc2;

    uint64_t zb[3][4];
#pragma unroll
    for (int i = 0; i < 3; ++i)
#pragma unroll
        for (int j = 0; j < 4; ++j)
            zb[i][j] = sz[(tr + i) * SZW + tc2 + 3 + j];   // col gw-1+j

    const float* xid = xn + gh * W + gw;
    float* op = out + (size_t)n * C * HW + gh * W + gw;
    bool leftE  = (gw == 0);
    bool rightE = (gw == W - 2);

    // wave-uniform row-border predicate (a wave spans 2 tile rows)
    bool slowW = (ty == 0 && tr < 2) || (ty == 15 && tr >= 14);

    // one (pixel-pair, channel) step: popc-conv + RPReLU + residual + store
    auto proc = [&](int oc, f32x2 iv) {
        const uint64_t* wp = wbitsP + oc * 10;   // uniform -> s_load
        int s0 = 0, s1 = 0;
#pragma unroll
        for (int i = 0; i < 3; ++i)
#pragma unroll
            for (int jj = 0; jj < 3; ++jj) {
                uint64_t wt = wp[i * 3 + jj];
                s0 += (int)__popcll(wt ^ zb[i][jj]);
                s1 += (int)__popcll(wt ^ zb[i][jj + 1]);
            }
        int d0 = 576 - 2 * s0, d1 = 576 - 2 * s1;
        int2 e = edg[oc];                        // uniform -> s_load
        if (leftE)  d0 += e.x;
        if (rightE) d1 += e.y;
        float4 pr = prm[oc];                     // uniform -> s_load_dwordx4
        f32x2 r;
        float y;
        y = pr.x * (float)d0 + pr.y; y = y > 0.f ? y : pr.z * y; r.x = y + pr.w + iv.x;
        y = pr.x * (float)d1 + pr.y; y = y > 0.f ? y : pr.z * y; r.y = y + pr.w + iv.y;
        __builtin_nontemporal_store(r, reinterpret_cast<f32x2*>(op + (size_t)oc * HW));
    };

    // ---- phase 3: o-loop ---------------------------------------------------
    if (!slowW) {
        // 4-deep identity prefetch pipeline (explicit named regs, static idx)
        f32x2 id0 = *reinterpret_cast<const f32x2*>(xid);
        f32x2 id1 = *reinterpret_cast<const f32x2*>(xid + (size_t)1 * HW);
        f32x2 id2 = *reinterpret_cast<const f32x2*>(xid + (size_t)2 * HW);
        f32x2 id3 = *reinterpret_cast<const f32x2*>(xid + (size_t)3 * HW);
        for (int o = 0; o < C; o += 4) {
            int p0 = o + 4 > C - 1 ? C - 1 : o + 4;   // clamp (dup ch63 loads
            int p1 = o + 5 > C - 1 ? C - 1 : o + 5;   //  on tail: L1 hits)
            int p2 = o + 6 > C - 1 ? C - 1 : o + 6;
            int p3 = o + 7 > C - 1 ? C - 1 : o + 7;
            f32x2 n0 = *reinterpret_cast<const f32x2*>(xid + (size_t)p0 * HW);
            f32x2 n1 = *reinterpret_cast<const f32x2*>(xid + (size_t)p1 * HW);
            f32x2 n2 = *reinterpret_cast<const f32x2*>(xid + (size_t)p2 * HW);
            f32x2 n3 = *reinterpret_cast<const f32x2*>(xid + (size_t)p3 * HW);
            proc(o + 0, id0);
            proc(o + 1, id1);
            proc(o + 2, id2);
            proc(o + 3, id3);
            id0 = n0; id1 = n1; id2 = n2; id3 = n3;
        }
    } else {
        // masked path: exact for interior rows too (vrow all -1)
        int vrow[3], vcol[4];
#pragma unroll
        for (int i = 0; i < 3; ++i)
            vrow[i] = ((unsigned)(gh - 1 + i) < (unsigned)H) ? -1 : 0;
#pragma unroll
        for (int j = 0; j < 4; ++j)
            vcol[j] = ((unsigned)(gw - 1 + j) < (unsigned)W) ? -1 : 0;
        int nr  = (vrow[0] & 1) + (vrow[1] & 1) + (vrow[2] & 1);
        int nv0 = nr * ((vcol[0] & 1) + (vcol[1] & 1) + (vcol[2] & 1));
        int nv1 = nr * ((vcol[1] & 1) + (vcol[2] & 1) + (vcol[3] & 1));
#pragma unroll 2
        for (int o = 0; o < C; ++o) {
            const uint64_t* wp = wbitsP + o * 10;
            int s0 = 0, s1 = 0;
#pragma unroll
            for (int i = 0; i < 3; ++i)
#pragma unroll
                for (int jj = 0; jj < 3; ++jj) {
                    uint64_t wt = wp[i * 3 + jj];
                    s0 += (vrow[i] & vcol[jj])     & (int)__popcll(wt ^ zb[i][jj]);
                    s1 += (vrow[i] & vcol[jj + 1]) & (int)__popcll(wt ^ zb[i][jj + 1]);
                }
            float4 pr = prm[o];
            f32x2 idv = *reinterpret_cast<const f32x2*>(xid + (size_t)o * HW);
            f32x2 r;
            float y;
            y = pr.x * (float)(64 * nv0 - 2 * s0) + pr.y; y = y > 0.f ? y : pr.z * y; r.x = y + pr.w + idv.x;
            y = pr.x * (float)(64 * nv1 - 2 * s1) + pr.y; y = y > 0.f ? y : pr.z * y; r.y = y + pr.w + idv.y;
            __builtin_nontemporal_store(r, reinterpret_cast<f32x2*>(op + (size_t)o * HW));
        }
    }
}

// ---------------------------------------------------------------------------
extern "C" void kernel_launch(void* const* d_in, const int* in_sizes, int n_in,
                              void* d_out, int out_size, void* d_ws, size_t ws_size,
                              hipStream_t stream) {
    const float* x           = (const float*)d_in[0];
    const float* move0_bias  = (const float*)d_in[1];
    const float* conv_weight = (const float*)d_in[2];
    const float* prelu_w     = (const float*)d_in[3];
    const float* pr_bias0    = (const float*)d_in[4];
    const float* pr_bias1    = (const float*)d_in[5];
    float* out = (float*)d_out;

    uint8_t* ws = (uint8_t*)d_ws;
    uint64_t* wbitsP = (uint64_t*)ws;                    // 64*10*8 = 5120 B
    float4* prm      = (float4*)(ws + 5120);             // 1024 B (16B-aligned)
    int2* edg        = (int2*)(ws + 6144);               // 512 B

    prep_weights<<<64, 64, 0, stream>>>(conv_weight, pr_bias0, prelu_w, pr_bias1,
                                        wbitsP, prm, edg);
    bconv_fused<<<Bn * (H / TH) * (W / TW), 512, 0, stream>>>(
        wbitsP, prm, edg, x, move0_bias, out);
}

// Round 6
// 516.291 us; speedup vs baseline: 1.0998x; 1.0048x over previous
//
#include <hip/hip_runtime.h>
#include <stdint.h>

#define Bn 16
#define C 64
#define H 256
#define W 256
#define HW (H * W)          // 65536
#define NHW (Bn * HW)       // 1048576

// Fused-kernel tile geometry: 64 wide x 16 high, 512 threads, 2 px/thread.
#define TW 64
#define TH 16
#define SZH 18              // TH + 2 halo rows
#define SZW 73              // 72 used cols (gw0-4 .. gw0+67), +1 pad

typedef float f32x4 __attribute__((ext_vector_type(4)));
typedef float f32x2 __attribute__((ext_vector_type(2)));

// ---------------------------------------------------------------------------
// Kernel 1: weight prep. One wave per output channel o.
// wbitsP[o*10+tap] bit c = (w[o][c][tap] > 0)  (padded to 10 u64/row, 16B-aligned)
// prm[o] = {scale, pb0, aw, pb1};  edg[o] = {edgeL-192, edgeR-192}
// ---------------------------------------------------------------------------
__global__ void prep_weights(const float* __restrict__ w,
                             const float* __restrict__ pb0,
                             const float* __restrict__ aw,
                             const float* __restrict__ pb1,
                             uint64_t* __restrict__ wbitsP,
                             float4* __restrict__ prm,
                             int2* __restrict__ edg) {
    int o = blockIdx.x;     // 64 blocks
    int c = threadIdx.x;    // 64 threads = 1 wave
    const float* wp = w + ((size_t)o * C + c) * 9;
    float asum = 0.f;
    uint64_t m[9];
#pragma unroll
    for (int tap = 0; tap < 9; ++tap) {
        float v = wp[tap];
        asum += fabsf(v);
        m[tap] = __ballot(v > 0.f);   // uniform across the wave
    }
    if (c == 0) {
#pragma unroll
        for (int tap = 0; tap < 9; ++tap) wbitsP[o * 10 + tap] = m[tap];
        wbitsP[o * 10 + 9] = 0;
        edg[o] = make_int2(
            2 * (int)(__popcll(m[0]) + __popcll(m[3]) + __popcll(m[6])) - 192,
            2 * (int)(__popcll(m[2]) + __popcll(m[5]) + __popcll(m[8])) - 192);
    }
#pragma unroll
    for (int off = 32; off > 0; off >>= 1)
        asum += __shfl_down(asum, off);
    if (c == 0) prm[o] = make_float4(asum * (1.f / 576.f), pb0[o], aw[o], pb1[o]);
}

// ---------------------------------------------------------------------------
// Kernel 2 (fused): pack z (tile + 1px halo) into LDS, then binary conv +
// RPReLU + residual. 512 threads, 2 px/thread. launch_bounds(512,2):
// 256-VGPR budget so the 8-deep identity pipeline and 8-wide pack batches
// stay register-resident (r5's 40 VGPRs proved the compiler honors named
// pipeline regs but adds no depth of its own). Weights/params are
// wave-uniform s_loads. Out-of-image z-words are 0; column borders fixed via
// edg[] on the unmasked sum; row borders take the fully-masked path,
// widened to whole waves (wave-uniform branch).
// ---------------------------------------------------------------------------
__global__ __launch_bounds__(512, 2) void bconv_fused(
        const uint64_t* __restrict__ wbitsP,
        const float4* __restrict__ prm,
        const int2* __restrict__ edg,
        const float* __restrict__ x,
        const float* __restrict__ bias,
        float* __restrict__ out) {
    __shared__ uint64_t sz[SZH * SZW];     // 10512 B

    int t = threadIdx.x;
    int bid = blockIdx.x;                  // 1024 blocks
    int n = bid >> 6;                      // image
    int tile = bid & 63;
    int ty = tile >> 2, tx = tile & 3;     // 16 down, 4 across
    int gh0 = ty * TH, gw0 = tx * TW;

    const float* xn = x + (size_t)n * C * HW;

    // ---- phase 1: pack z into LDS (18 rows x 18 four-col chunks),
    //      8x8 batched loads with next-batch prefetch -------------------------
    if (t < SZH * 18) {
        int r = t / 18;
        int cb = (t - r * 18) * 4;         // col offset within sz row
        int gh = gh0 + r - 1;
        int gwb = gw0 - 4 + cb;            // global col of chunk base (4-aligned)
        uint64_t b0 = 0, b1 = 0, b2 = 0, b3 = 0;
        if ((unsigned)gh < (unsigned)H && (unsigned)gwb <= (unsigned)(W - 4)) {
            const float* xp = xn + gh * W + gwb;
            f32x4 cur[8], nxt[8];
#pragma unroll
            for (int k = 0; k < 8; ++k)
                cur[k] = *reinterpret_cast<const f32x4*>(xp + (size_t)k * HW);
            for (int b8 = 0; b8 < 8; ++b8) {
                if (b8 < 7) {
#pragma unroll
                    for (int k = 0; k < 8; ++k)
                        nxt[k] = *reinterpret_cast<const f32x4*>(
                            xp + (size_t)((b8 + 1) * 8 + k) * HW);
                }
#pragma unroll
                for (int k = 0; k < 8; ++k) {
                    int ch = b8 * 8 + k;
                    float bc = bias[ch];   // uniform -> scalar load
                    f32x4 v = cur[k];
                    b0 |= (uint64_t)(v.x + bc > 0.f) << ch;
                    b1 |= (uint64_t)(v.y + bc > 0.f) << ch;
                    b2 |= (uint64_t)(v.z + bc > 0.f) << ch;
                    b3 |= (uint64_t)(v.w + bc > 0.f) << ch;
                }
                if (b8 < 7) {
#pragma unroll
                    for (int k = 0; k < 8; ++k) cur[k] = nxt[k];
                }
            }
        }
        uint64_t* zp = &sz[r * SZW + cb];
        zp[0] = b0; zp[1] = b1; zp[2] = b2; zp[3] = b3;
    }
    __syncthreads();

    // ---- phase 2: this thread's 3x4 z window from LDS ----------------------
    int tr = t >> 5;                       // tile row 0..15 (32 thr/row)
    int tc2 = (t & 31) * 2;                // tile col base (2 px/thread)
    int gh = gh0 + tr;
    int gw = gw0 + tc2;

    uint64_t zb[3][4];
#pragma unroll
    for (int i = 0; i < 3; ++i)
#pragma unroll
        for (int j = 0; j < 4; ++j)
            zb[i][j] = sz[(tr + i) * SZW + tc2 + 3 + j];   // col gw-1+j

    const float* xid = xn + gh * W + gw;
    float* op = out + (size_t)n * C * HW + gh * W + gw;
    bool leftE  = (gw == 0);
    bool rightE = (gw == W - 2);

    // wave-uniform row-border predicate (a wave spans 2 tile rows)
    bool slowW = (ty == 0 && tr < 2) || (ty == 15 && tr >= 14);

    // one (pixel-pair, channel) step: popc-conv + RPReLU + residual + store
    auto proc = [&](int oc, f32x2 iv) {
        const uint64_t* wp = wbitsP + oc * 10;   // uniform -> s_load
        int s0 = 0, s1 = 0;
#pragma unroll
        for (int i = 0; i < 3; ++i)
#pragma unroll
            for (int jj = 0; jj < 3; ++jj) {
                uint64_t wt = wp[i * 3 + jj];
                s0 += (int)__popcll(wt ^ zb[i][jj]);
                s1 += (int)__popcll(wt ^ zb[i][jj + 1]);
            }
        int d0 = 576 - 2 * s0, d1 = 576 - 2 * s1;
        int2 e = edg[oc];                        // uniform -> s_load
        if (leftE)  d0 += e.x;
        if (rightE) d1 += e.y;
        float4 pr = prm[oc];                     // uniform -> s_load_dwordx4
        f32x2 r;
        float y;
        y = pr.x * (float)d0 + pr.y; y = y > 0.f ? y : pr.z * y; r.x = y + pr.w + iv.x;
        y = pr.x * (float)d1 + pr.y; y = y > 0.f ? y : pr.z * y; r.y = y + pr.w + iv.y;
        __builtin_nontemporal_store(r, reinterpret_cast<f32x2*>(op + (size_t)oc * HW));
    };

    // ---- phase 3: o-loop, groups of 8 with 8-deep identity prefetch --------
    if (!slowW) {
        f32x2 idv[8], nid[8];
#pragma unroll
        for (int k = 0; k < 8; ++k)
            idv[k] = *reinterpret_cast<const f32x2*>(xid + (size_t)k * HW);
        for (int g = 0; g < 8; ++g) {
            int ob = g * 8;
            if (g < 7) {
#pragma unroll
                for (int k = 0; k < 8; ++k)
                    nid[k] = *reinterpret_cast<const f32x2*>(
                        xid + (size_t)(ob + 8 + k) * HW);
            }
#pragma unroll
            for (int k = 0; k < 8; ++k) proc(ob + k, idv[k]);
            if (g < 7) {
#pragma unroll
                for (int k = 0; k < 8; ++k) idv[k] = nid[k];
            }
        }
    } else {
        // masked path: exact for interior rows too (vrow all -1)
        int vrow[3], vcol[4];
#pragma unroll
        for (int i = 0; i < 3; ++i)
            vrow[i] = ((unsigned)(gh - 1 + i) < (unsigned)H) ? -1 : 0;
#pragma unroll
        for (int j = 0; j < 4; ++j)
            vcol[j] = ((unsigned)(gw - 1 + j) < (unsigned)W) ? -1 : 0;
        int nr  = (vrow[0] & 1) + (vrow[1] & 1) + (vrow[2] & 1);
        int nv0 = nr * ((vcol[0] & 1) + (vcol[1] & 1) + (vcol[2] & 1));
        int nv1 = nr * ((vcol[1] & 1) + (vcol[2] & 1) + (vcol[3] & 1));
#pragma unroll 2
        for (int o = 0; o < C; ++o) {
            const uint64_t* wp = wbitsP + o * 10;
            int s0 = 0, s1 = 0;
#pragma unroll
            for (int i = 0; i < 3; ++i)
#pragma unroll
                for (int jj = 0; jj < 3; ++jj) {
                    uint64_t wt = wp[i * 3 + jj];
                    s0 += (vrow[i] & vcol[jj])     & (int)__popcll(wt ^ zb[i][jj]);
                    s1 += (vrow[i] & vcol[jj + 1]) & (int)__popcll(wt ^ zb[i][jj + 1]);
                }
            float4 pr = prm[o];
            f32x2 idv = *reinterpret_cast<const f32x2*>(xid + (size_t)o * HW);
            f32x2 r;
            float y;
            y = pr.x * (float)(64 * nv0 - 2 * s0) + pr.y; y = y > 0.f ? y : pr.z * y; r.x = y + pr.w + idv.x;
            y = pr.x * (float)(64 * nv1 - 2 * s1) + pr.y; y = y > 0.f ? y : pr.z * y; r.y = y + pr.w + idv.y;
            __builtin_nontemporal_store(r, reinterpret_cast<f32x2*>(op + (size_t)o * HW));
        }
    }
}

// ---------------------------------------------------------------------------
extern "C" void kernel_launch(void* const* d_in, const int* in_sizes, int n_in,
                              void* d_out, int out_size, void* d_ws, size_t ws_size,
                              hipStream_t stream) {
    const float* x           = (const float*)d_in[0];
    const float* move0_bias  = (const float*)d_in[1];
    const float* conv_weight = (const float*)d_in[2];
    const float* prelu_w     = (const float*)d_in[3];
    const float* pr_bias0    = (const float*)d_in[4];
    const float* pr_bias1    = (const float*)d_in[5];
    float* out = (float*)d_out;

    uint8_t* ws = (uint8_t*)d_ws;
    uint64_t* wbitsP = (uint64_t*)ws;                    // 64*10*8 = 5120 B
    float4* prm      = (float4*)(ws + 5120);             // 1024 B (16B-aligned)
    int2* edg        = (int2*)(ws + 6144);               // 512 B

    prep_weights<<<64, 64, 0, stream>>>(conv_weight, pr_bias0, prelu_w, pr_bias1,
                                        wbitsP, prm, edg);
    bconv_fused<<<Bn * (H / TH) * (W / TW), 512, 0, stream>>>(
        wbitsP, prm, edg, x, move0_bias, out);
}